// Round 17
// baseline (403.246 us; speedup 1.0000x reference)
//
#include <hip/hip_runtime.h>
#include <hip/hip_fp16.h>
#include <math.h>
#include <stdint.h>

#define B_ 4
#define N_ 512
#define D_ 64
#define NDIAG (2 * N_ - 1)
#define WV 4                 // consumer waves (+ WV producer waves)
#define K_ 16
#define DC0 9
#define NCH 40
#define CTOT (DC0 * (WV - 1) + NCH)  // 67
#define RING 1028
#define BIGF 1e30f

typedef unsigned int uint32x4 __attribute__((ext_vector_type(4)));

__global__ __launch_bounds__(256) void dist_h_kernel(
    const float* __restrict__ x, const float* __restrict__ y,
    __half* __restrict__ dd2)
{
    const int b = blockIdx.z;
    const int i0 = blockIdx.y * 16;
    const int j0 = blockIdx.x * 16;
    __shared__ float xs[16 * 68];
    __shared__ float ys[16 * 68];
    const int t = threadIdx.x;
    const int lr = t >> 4;
    const int lc = t & 15;
    const float4* xsrc = (const float4*)(x + (((size_t)b * N_) + i0 + lr) * D_);
    const float4* ysrc = (const float4*)(y + (((size_t)b * N_) + j0 + lr) * D_);
    *(float4*)(&xs[lr * 68 + lc * 4]) = xsrc[lc];
    *(float4*)(&ys[lr * 68 + lc * 4]) = ysrc[lc];
    __syncthreads();

    const int ti = t >> 4, tj = t & 15;
    const float* xr = &xs[ti * 68];
    const float* yr = &ys[tj * 68];
    float acc = 0.f;
#pragma unroll
    for (int k = 0; k < 16; ++k) {
        float4 a = *(const float4*)(xr + 4 * k);
        float4 c = *(const float4*)(yr + 4 * k);
        float d0 = a.x - c.x, d1 = a.y - c.y, d2 = a.z - c.z, d3 = a.w - c.w;
        acc += d0 * d0 + d1 * d1 + d2 * d2 + d3 * d3;
    }
    const int i = i0 + ti, j = j0 + tj;
    const int r = i + j, g = r >> 2, rs = r & 3, j2 = j >> 1, p = j & 1;
    dd2[(((((size_t)b << 8) | g) << 8) | j2) * 8 + rs * 2 + p] =
        __float2half(sqrtf(acc));
}

__device__ __forceinline__ float dpp_shr1(float x) {
    int v = __builtin_amdgcn_update_dpp(0x7f800000, __float_as_int(x),
                                        0x138, 0xf, 0xf, false);
    return __int_as_float(v);
}
__device__ __forceinline__ float vmin3(float a, float b, float c) {
    float r; asm("v_min3_f32 %0, %1, %2, %3" : "=v"(r) : "v"(a), "v"(b), "v"(c)); return r;
}
__device__ __forceinline__ float vmed3(float a, float b, float c) {
    float r; asm("v_med3_f32 %0, %1, %2, %3" : "=v"(r) : "v"(a), "v"(b), "v"(c)); return r;
}
__device__ __forceinline__ float vmax3(float a, float b, float c) {
    float r; asm("v_max3_f32 %0, %1, %2, %3" : "=v"(r) : "v"(a), "v"(b), "v"(c)); return r;
}
#if __has_builtin(__builtin_amdgcn_exp2f)
#define EXP2(x) __builtin_amdgcn_exp2f(x)
#else
#define EXP2(x) exp2f(x)
#endif
#if __has_builtin(__builtin_amdgcn_logf)
#define LOG2(x) __builtin_amdgcn_logf(x)
#else
#define LOG2(x) log2f(x)
#endif
__device__ __forceinline__ float2 h2f(unsigned u) {
    union { unsigned u; __half2 h; } cv; cv.u = u;
    return __half22float2(cv.h);
}

// Single-factor variants of R16's producer/consumer kernel:
// VAR 0 = full (exact, d_out)      VAR 1 = const-d (cq tied, d constant)
// VAR 2 = no-ring (real d)         VAR 3 = stale-pbuf (producers never store)
template <int VAR>
__device__ __forceinline__ void sdtw_pc_body(
    const __half* __restrict__ dd2, float* __restrict__ out,
    float* __restrict__ dump)
{
    constexpr bool CONSTD = (VAR == 1);
    constexpr bool RNG    = (VAR != 2);
    constexpr bool PSTORE = (VAR != 3);

    const int b = blockIdx.x;
    const int tid = threadIdx.x;
    const int wid = tid >> 6;
    const int lane = tid & 63;
    const bool isCons = (wid < WV);
    const int w = isCons ? wid : wid - WV;

    if constexpr (VAR == 0) {
        out[b * N_ + tid] = (float)tid;
        out[B_ * N_ + b * N_ + tid] = (float)tid;
    }

    __shared__ __align__(16) float ring[WV + 1][RING];
    __shared__ __align__(16) __half pbuf[WV][2][K_ * 128];
    for (int q = tid; q < (WV + 1) * RING; q += 512)
        (&ring[0][0])[q] = (q == 0) ? 0.0f : BIGF;

    const float C1 = 14.4269504089f;
    const float C2 = -0.069314718056f;
    const int c0w = DC0 * w;
    const int s0w = 128 * w + 2;
    const bool l0 = (lane == 0);
    const bool l63 = (lane == 63);
    const float* ringR = ring[w];
    float* ringW = ring[w + 1];
    const uint64_t wbase = (uint64_t)dd2 + ((uint64_t)b << 20)
                         + (uint64_t)(64 * w + lane) * 16
                         + ((uint64_t)(32 * w) << 12);

    float2 dval = {1.0f, 1.0f};
    if constexpr (CONSTD) {
        unsigned dv = *(const unsigned*)(wbase);
        asm volatile("" : "+v"(dv));
        dval = h2f(dv);
    }

    // prologue staging
    if constexpr (PSTORE) {
        if (wid == WV) {  // producer for w=0: stage chunk 0
            const uint32x4 v0 = *(const uint32x4*)(wbase);
            const uint32x4 v1 = *(const uint32x4*)(wbase + 4096);
            const uint32x4 v2 = *(const uint32x4*)(wbase + 8192);
            const uint32x4 v3 = *(const uint32x4*)(wbase + 12288);
            char* dst = (char*)&pbuf[0][0][0] + lane * 16;
            *(uint32x4*)(dst)        = v0;
            *(uint32x4*)(dst + 1024) = v1;
            *(uint32x4*)(dst + 2048) = v2;
            *(uint32x4*)(dst + 3072) = v3;
        }
    } else {
        if (!isCons) {  // VAR3: every producer pre-stages chunks 0,1 once
#pragma unroll
            for (int cc = 0; cc < 2; ++cc) {
                const uint64_t g0 = wbase + ((uint64_t)(cc * 4) << 12);
                const uint32x4 v0 = *(const uint32x4*)(g0);
                const uint32x4 v1 = *(const uint32x4*)(g0 + 4096);
                const uint32x4 v2 = *(const uint32x4*)(g0 + 8192);
                const uint32x4 v3 = *(const uint32x4*)(g0 + 12288);
                char* dst = (char*)&pbuf[w][cc][0] + lane * 16;
                *(uint32x4*)(dst)        = v0;
                *(uint32x4*)(dst + 1024) = v1;
                *(uint32x4*)(dst + 2048) = v2;
                *(uint32x4*)(dst + 3072) = v3;
            }
        }
    }
    __syncthreads();

    unsigned u0 = (unsigned)(-(2 * lane));
    float rA0 = BIGF, rB0 = BIGF, rA1 = BIGF;
    float lnL = BIGF, ldL = BIGF;
    float res = 0.0f;

#define STEP(d0_, d1_, tt_, rrn_)                                           \
    {                                                                       \
        float m0  = vmin3(rA0, lnL, ldL);                                   \
        float md0 = vmed3(rA0, lnL, ldL);                                   \
        float mx0 = vmax3(rA0, lnL, ldL);                                   \
        float e0 = EXP2((m0 - md0) * C1);                                   \
        float f0 = EXP2((m0 - mx0) * C1);                                   \
        float r0 = fmaf(C2, LOG2(1.0f + e0 + f0), m0 + (d0_));              \
        float m1  = vmin3(rA1, rA0, rB0);                                   \
        float md1 = vmed3(rA1, rA0, rB0);                                   \
        float mx1 = vmax3(rA1, rA0, rB0);                                   \
        float e1 = EXP2((m1 - md1) * C1);                                   \
        float f1 = EXP2((m1 - mx1) * C1);                                   \
        float r1 = fmaf(C2, LOG2(1.0f + e1 + f1), m1 + (d1_));              \
        res = (u0 == 512u) ? r1 : res;                                      \
        u0 += 1u;                                                           \
        rB0 = rA0; rA0 = r0;                                                \
        ldL = lnL;                                                          \
        float sh = dpp_shr1(r1);                                            \
        lnL = l0 ? (rrn_) : sh;                                             \
        rA1 = r1;                                                           \
        if constexpr (RNG) { if (l63) ringW[s0c + (tt_)] = r1; }            \
    }
#define GBLOCK(q_, gi_, rA_, rB_, rC_, rD_)                                 \
    {                                                                       \
        float2 fa_, fb_, fc_, fd_;                                          \
        if constexpr (CONSTD) {                                             \
            fa_ = dval; fb_ = dval; fc_ = dval; fd_ = dval;                 \
        } else {                                                            \
            fa_ = h2f((q_)[0]); fb_ = h2f((q_)[1]);                         \
            fc_ = h2f((q_)[2]); fd_ = h2f((q_)[3]);                         \
        }                                                                   \
        STEP(fa_.x, fa_.y, 4 * (gi_) + 0, rA_)                              \
        STEP(fb_.x, fb_.y, 4 * (gi_) + 1, rB_)                              \
        STEP(fc_.x, fc_.y, 4 * (gi_) + 2, rC_)                              \
        STEP(fd_.x, fd_.y, 4 * (gi_) + 3, rD_)                              \
    }

    for (int c = 0; c < CTOT; ++c) {
        const int lc = c - c0w;
        if (isCons) {
            if (lc >= 0 && lc < NCH) {
                const int s0c = s0w + lc * K_;
                const char* cb = (const char*)&pbuf[w][lc & 1][0] + lane * 16;
                const uint32x4 cq0 = *(const uint32x4*)(cb);
                const uint32x4 cq1 = *(const uint32x4*)(cb + 1024);
                const uint32x4 cq2 = *(const uint32x4*)(cb + 2048);
                const uint32x4 cq3 = *(const uint32x4*)(cb + 3072);
                if constexpr (CONSTD) {  // reads stay, results tied (r#17)
                    asm volatile("" :: "v"(cq0), "v"(cq1), "v"(cq2), "v"(cq3));
                }
                float rr0, rr1, rr2, rr3, rr4, rr5, rr6, rr7, rr8, rr9,
                      rr10, rr11, rr12, rr13, rr14, rr15, rr16, rr17;
                if constexpr (RNG) {
                    const float4 p0 = *(const float4*)&ringR[s0c - 2];
                    const float4 p1 = *(const float4*)&ringR[s0c + 2];
                    const float4 p2 = *(const float4*)&ringR[s0c + 6];
                    const float4 p3 = *(const float4*)&ringR[s0c + 10];
                    const float2 p4 = *(const float2*)&ringR[s0c + 14];
                    rr0 = p0.x; rr1 = p0.y; rr2 = p0.z; rr3 = p0.w;
                    rr4 = p1.x; rr5 = p1.y; rr6 = p1.z; rr7 = p1.w;
                    rr8 = p2.x; rr9 = p2.y; rr10 = p2.z; rr11 = p2.w;
                    rr12 = p3.x; rr13 = p3.y; rr14 = p3.z; rr15 = p3.w;
                    rr16 = p4.x; rr17 = p4.y;
                } else {
                    rr0 = rr1 = rr2 = rr3 = rr4 = rr5 = rr6 = rr7 = rr8 =
                    rr9 = rr10 = rr11 = rr12 = rr13 = rr14 = rr15 = rr16 =
                    rr17 = BIGF;
                }
                if (lc == 0) {
                    lnL = l0 ? rr1 : BIGF;
                    ldL = l0 ? rr0 : BIGF;
                }
                GBLOCK(cq0, 0, rr2,  rr3,  rr4,  rr5)
                GBLOCK(cq1, 1, rr6,  rr7,  rr8,  rr9)
                GBLOCK(cq2, 2, rr10, rr11, rr12, rr13)
                GBLOCK(cq3, 3, rr14, rr15, rr16, rr17)
            }
        } else {
            const int wc = lc + 1;
            if (wc >= 0 && wc < NCH) {
                const uint64_t g0 = wbase + ((uint64_t)(wc * 4) << 12);
                const uint32x4 v0 = *(const uint32x4*)(g0);
                const uint32x4 v1 = *(const uint32x4*)(g0 + 4096);
                const uint32x4 v2 = *(const uint32x4*)(g0 + 8192);
                const uint32x4 v3 = *(const uint32x4*)(g0 + 12288);
                if constexpr (PSTORE) {
                    char* dst = (char*)&pbuf[w][wc & 1][0] + lane * 16;
                    *(uint32x4*)(dst)        = v0;
                    *(uint32x4*)(dst + 1024) = v1;
                    *(uint32x4*)(dst + 2048) = v2;
                    *(uint32x4*)(dst + 3072) = v3;
                } else {
                    asm volatile("" :: "v"(v0), "v"(v1), "v"(v2), "v"(v3));
                }
            }
        }
        asm volatile("s_waitcnt lgkmcnt(0)" ::: "memory");
        __builtin_amdgcn_s_barrier();
    }
#undef GBLOCK
#undef STEP

    if constexpr (VAR == 0) {
        if (wid == WV - 1 && l63) out[2 * B_ * N_ + b] = res;
    } else {
        asm volatile("" :: "v"(rA0), "v"(rB0), "v"(res));
        if (wid == WV - 1 && l63) dump[b] = res;
    }
}

__global__ __launch_bounds__(512, 1) void sdtw_full_kernel(
    const __half* __restrict__ dd2, float* out, float* dump)
{ sdtw_pc_body<0>(dd2, out, dump); }

__global__ __launch_bounds__(512, 1) void sdtw_cda_kernel(
    const __half* __restrict__ dd2, float* out, float* dump)
{ sdtw_pc_body<1>(dd2, out, dump); }

__global__ __launch_bounds__(512, 1) void sdtw_nrg_kernel(
    const __half* __restrict__ dd2, float* out, float* dump)
{ sdtw_pc_body<2>(dd2, out, dump); }

__global__ __launch_bounds__(512, 1) void sdtw_stp_kernel(
    const __half* __restrict__ dd2, float* out, float* dump)
{ sdtw_pc_body<3>(dd2, out, dump); }

extern "C" void kernel_launch(void* const* d_in, const int* in_sizes, int n_in,
                              void* d_out, int out_size, void* d_ws, size_t ws_size,
                              hipStream_t stream) {
    const float* x = (const float*)d_in[0];
    const float* y = (const float*)d_in[1];
    float* out = (float*)d_out;
    __half* dd2 = (__half*)d_ws;                       // 4 MB packed table
    float* dump = (float*)((char*)d_ws + (6u << 20));  // probe dumps

    dim3 g1(N_ / 16, N_ / 16, B_);
    dist_h_kernel<<<g1, 256, 0, stream>>>(x, y, dd2);
    sdtw_full_kernel<<<B_, 512, 0, stream>>>(dd2, out, dump);       // exact
    sdtw_cda_kernel<<<B_, 512, 0, stream>>>(dd2, nullptr, dump + 16);
    sdtw_nrg_kernel<<<B_, 512, 0, stream>>>(dd2, nullptr, dump + 32);
    sdtw_stp_kernel<<<B_, 512, 0, stream>>>(dd2, nullptr, dump + 48);
}

// Round 18
// 116.811 us; speedup vs baseline: 3.4521x; 3.4521x over previous
//
#include <hip/hip_runtime.h>
#include <hip/hip_fp16.h>
#include <math.h>
#include <stdint.h>

#define B_ 4
#define N_ 512
#define D_ 64
#define NDIAG (2 * N_ - 1)
#define WV 4                 // consumer waves (+ WV producer waves)
#define K_ 16
#define DC0 9
#define NCH 40
#define CTOT (DC0 * (WV - 1) + NCH)  // 67
#define RING 1028
#define BIGF 1e30f

typedef unsigned int uint32x4 __attribute__((ext_vector_type(4)));

// Phase 1: D in FP16, group-packed: half idx = ((b*256+g)*256 + j2)*8 + rs*2+p
// (r=i+j, g=r/4, rs=r%4, j2=j/2, p=j%2) -> 16B lane-load = 4 rows x 2 cols.
__global__ __launch_bounds__(256) void dist_h_kernel(
    const float* __restrict__ x, const float* __restrict__ y,
    __half* __restrict__ dd2)
{
    const int b = blockIdx.z;
    const int i0 = blockIdx.y * 16;
    const int j0 = blockIdx.x * 16;
    __shared__ float xs[16 * 68];
    __shared__ float ys[16 * 68];
    const int t = threadIdx.x;
    const int lr = t >> 4;
    const int lc = t & 15;
    const float4* xsrc = (const float4*)(x + (((size_t)b * N_) + i0 + lr) * D_);
    const float4* ysrc = (const float4*)(y + (((size_t)b * N_) + j0 + lr) * D_);
    *(float4*)(&xs[lr * 68 + lc * 4]) = xsrc[lc];
    *(float4*)(&ys[lr * 68 + lc * 4]) = ysrc[lc];
    __syncthreads();

    const int ti = t >> 4, tj = t & 15;
    const float* xr = &xs[ti * 68];
    const float* yr = &ys[tj * 68];
    float acc = 0.f;
#pragma unroll
    for (int k = 0; k < 16; ++k) {
        float4 a = *(const float4*)(xr + 4 * k);
        float4 c = *(const float4*)(yr + 4 * k);
        float d0 = a.x - c.x, d1 = a.y - c.y, d2 = a.z - c.z, d3 = a.w - c.w;
        acc += d0 * d0 + d1 * d1 + d2 * d2 + d3 * d3;
    }
    const int i = i0 + ti, j = j0 + tj;
    const int r = i + j, g = r >> 2, rs = r & 3, j2 = j >> 1, p = j & 1;
    dd2[(((((size_t)b << 8) | g) << 8) | j2) * 8 + rs * 2 + p] =
        __float2half(sqrtf(acc));
}

__device__ __forceinline__ float dpp_shr1(float x) {
    int v = __builtin_amdgcn_update_dpp(0x7f800000, __float_as_int(x),
                                        0x138, 0xf, 0xf, false);
    return __int_as_float(v);
}
__device__ __forceinline__ float vmin3(float a, float b, float c) {
    float r; asm("v_min3_f32 %0, %1, %2, %3" : "=v"(r) : "v"(a), "v"(b), "v"(c)); return r;
}
__device__ __forceinline__ float vmed3(float a, float b, float c) {
    float r; asm("v_med3_f32 %0, %1, %2, %3" : "=v"(r) : "v"(a), "v"(b), "v"(c)); return r;
}
__device__ __forceinline__ float vmax3(float a, float b, float c) {
    float r; asm("v_max3_f32 %0, %1, %2, %3" : "=v"(r) : "v"(a), "v"(b), "v"(c)); return r;
}
#if __has_builtin(__builtin_amdgcn_exp2f)
#define EXP2(x) __builtin_amdgcn_exp2f(x)
#else
#define EXP2(x) exp2f(x)
#endif
#if __has_builtin(__builtin_amdgcn_logf)
#define LOG2(x) __builtin_amdgcn_logf(x)
#else
#define LOG2(x) log2f(x)
#endif
__device__ __forceinline__ float2 h2f(unsigned u) {
    union { unsigned u; __half2 h; } cv; cv.u = u;
    return __half22float2(cv.h);
}

// Phase 2: producer/consumer with PIPELINED producers. Each producer keeps
// chunk wc in named registers loaded during the PREVIOUS interval; per
// interval: issue plain loads of wc+1, then store wc to pbuf (compiler's
// waitcnt covers loads issued ~1 interval ago -> exposed wait ~0). R17's
// ablation showed every slow variant had an exposed in-interval memory wait
// (even "stp": its tie forced the wait); R5's V1/V3 (no waits) ran ~8x
// faster with identical barriers/stagger/chain.
__global__ __launch_bounds__(512, 1) void sdtw_pc4_kernel(
    const __half* __restrict__ dd2, float* __restrict__ out)
{
    const int b = blockIdx.x;
    const int tid = threadIdx.x;
    const int wid = tid >> 6;
    const int lane = tid & 63;
    const bool isCons = (wid < WV);
    const int w = isCons ? wid : wid - WV;

    out[b * N_ + tid] = (float)tid;
    out[B_ * N_ + b * N_ + tid] = (float)tid;

    __shared__ __align__(16) float ring[WV + 1][RING];          // 20.6 KB
    __shared__ __align__(16) __half pbuf[WV][2][K_ * 128];      // 32 KB
    for (int q = tid; q < (WV + 1) * RING; q += 512)
        (&ring[0][0])[q] = (q == 0) ? 0.0f : BIGF;

    const float C1 = 14.4269504089f;
    const float C2 = -0.069314718056f;
    const int c0w = DC0 * w;
    const int s0w = 128 * w + 2;
    const bool l0 = (lane == 0);
    const bool l63 = (lane == 63);
    const float* ringR = ring[w];
    float* ringW = ring[w + 1];
    const uint64_t wbase = (uint64_t)dd2 + ((uint64_t)b << 20)
                         + (uint64_t)(64 * w + lane) * 16
                         + ((uint64_t)(32 * w) << 12);

    // producer double register buffer: A holds odd chunks, B even chunks
    uint32x4 pA0{}, pA1{}, pA2{}, pA3{};
    uint32x4 pB0{}, pB1{}, pB2{}, pB3{};

    // w=0 producer prologue: chunk 0 -> pbuf[0][0]; chunk 1 -> A regs.
    // __syncthreads drains vmcnt+lgkm for all waves -> sealed.
    if (wid == WV) {
        const uint32x4 v0 = *(const uint32x4*)(wbase);
        const uint32x4 v1 = *(const uint32x4*)(wbase + 4096);
        const uint32x4 v2 = *(const uint32x4*)(wbase + 8192);
        const uint32x4 v3 = *(const uint32x4*)(wbase + 12288);
        char* dst = (char*)&pbuf[0][0][0] + lane * 16;
        *(uint32x4*)(dst)        = v0;
        *(uint32x4*)(dst + 1024) = v1;
        *(uint32x4*)(dst + 2048) = v2;
        *(uint32x4*)(dst + 3072) = v3;
        const uint64_t g1 = wbase + (4ull << 12);  // chunk 1
        pA0 = *(const uint32x4*)(g1);
        pA1 = *(const uint32x4*)(g1 + 4096);
        pA2 = *(const uint32x4*)(g1 + 8192);
        pA3 = *(const uint32x4*)(g1 + 12288);
    }
    __syncthreads();

    unsigned u0 = (unsigned)(-(2 * lane));
    float rA0 = BIGF, rB0 = BIGF, rA1 = BIGF;
    float lnL = BIGF, ldL = BIGF;
    float res = 0.0f;

#define STEP(d0_, d1_, tt_, rrn_)                                           \
    {                                                                       \
        float m0  = vmin3(rA0, lnL, ldL);                                   \
        float md0 = vmed3(rA0, lnL, ldL);                                   \
        float mx0 = vmax3(rA0, lnL, ldL);                                   \
        float e0 = EXP2((m0 - md0) * C1);                                   \
        float f0 = EXP2((m0 - mx0) * C1);                                   \
        float r0 = fmaf(C2, LOG2(1.0f + e0 + f0), m0 + (d0_));              \
        float m1  = vmin3(rA1, rA0, rB0);                                   \
        float md1 = vmed3(rA1, rA0, rB0);                                   \
        float mx1 = vmax3(rA1, rA0, rB0);                                   \
        float e1 = EXP2((m1 - md1) * C1);                                   \
        float f1 = EXP2((m1 - mx1) * C1);                                   \
        float r1 = fmaf(C2, LOG2(1.0f + e1 + f1), m1 + (d1_));              \
        res = (u0 == 512u) ? r1 : res;                                      \
        u0 += 1u;                                                           \
        rB0 = rA0; rA0 = r0;                                                \
        ldL = lnL;                                                          \
        float sh = dpp_shr1(r1);                                            \
        lnL = l0 ? (rrn_) : sh;                                             \
        rA1 = r1;                                                           \
        if (l63) ringW[s0c + (tt_)] = r1;                                   \
    }
#define GBLOCK(q_, gi_, rA_, rB_, rC_, rD_)                                 \
    {                                                                       \
        const float2 fa_ = h2f((q_)[0]);                                    \
        const float2 fb_ = h2f((q_)[1]);                                    \
        const float2 fc_ = h2f((q_)[2]);                                    \
        const float2 fd_ = h2f((q_)[3]);                                    \
        STEP(fa_.x, fa_.y, 4 * (gi_) + 0, rA_)                              \
        STEP(fb_.x, fb_.y, 4 * (gi_) + 1, rB_)                              \
        STEP(fc_.x, fc_.y, 4 * (gi_) + 2, rC_)                              \
        STEP(fd_.x, fd_.y, 4 * (gi_) + 3, rD_)                              \
    }

    for (int c = 0; c < CTOT; ++c) {
        const int lc = c - c0w;
        if (isCons) {
            if (lc >= 0 && lc < NCH) {
                const int s0c = s0w + lc * K_;
                const char* cb = (const char*)&pbuf[w][lc & 1][0] + lane * 16;
                const uint32x4 cq0 = *(const uint32x4*)(cb);
                const uint32x4 cq1 = *(const uint32x4*)(cb + 1024);
                const uint32x4 cq2 = *(const uint32x4*)(cb + 2048);
                const uint32x4 cq3 = *(const uint32x4*)(cb + 3072);
                const float4 p0 = *(const float4*)&ringR[s0c - 2];
                const float4 p1 = *(const float4*)&ringR[s0c + 2];
                const float4 p2 = *(const float4*)&ringR[s0c + 6];
                const float4 p3 = *(const float4*)&ringR[s0c + 10];
                const float2 p4 = *(const float2*)&ringR[s0c + 14];
                const float rr0 = p0.x, rr1 = p0.y, rr2 = p0.z, rr3 = p0.w;
                const float rr4 = p1.x, rr5 = p1.y, rr6 = p1.z, rr7 = p1.w;
                const float rr8 = p2.x, rr9 = p2.y, rr10 = p2.z, rr11 = p2.w;
                const float rr12 = p3.x, rr13 = p3.y, rr14 = p3.z, rr15 = p3.w;
                const float rr16 = p4.x, rr17 = p4.y;
                if (lc == 0) {
                    lnL = l0 ? rr1 : BIGF;
                    ldL = l0 ? rr0 : BIGF;
                }
                GBLOCK(cq0, 0, rr2,  rr3,  rr4,  rr5)
                GBLOCK(cq1, 1, rr6,  rr7,  rr8,  rr9)
                GBLOCK(cq2, 2, rr10, rr11, rr12, rr13)
                GBLOCK(cq3, 3, rr14, rr15, rr16, rr17)
            }
        } else {
            // pipelined producer. wc = chunk to store this interval (regs
            // loaded last interval); also issue loads of wc+1.
            const int wc = lc + 1;
            if (lc == -2) {
                // preload chunk 0 (even) into B
                pB0 = *(const uint32x4*)(wbase);
                pB1 = *(const uint32x4*)(wbase + 4096);
                pB2 = *(const uint32x4*)(wbase + 8192);
                pB3 = *(const uint32x4*)(wbase + 12288);
            } else if (wc >= 0 && wc < NCH) {
                if (wc & 1) {
                    // store A (odd chunk wc); load wc+1 (even) into B
                    if (wc + 1 < NCH) {
                        const uint64_t g0 = wbase + ((uint64_t)((wc + 1) * 4) << 12);
                        pB0 = *(const uint32x4*)(g0);
                        pB1 = *(const uint32x4*)(g0 + 4096);
                        pB2 = *(const uint32x4*)(g0 + 8192);
                        pB3 = *(const uint32x4*)(g0 + 12288);
                    }
                    char* dst = (char*)&pbuf[w][1][0] + lane * 16;
                    *(uint32x4*)(dst)        = pA0;
                    *(uint32x4*)(dst + 1024) = pA1;
                    *(uint32x4*)(dst + 2048) = pA2;
                    *(uint32x4*)(dst + 3072) = pA3;
                } else {
                    // store B (even chunk wc); load wc+1 (odd) into A
                    if (wc + 1 < NCH) {
                        const uint64_t g0 = wbase + ((uint64_t)((wc + 1) * 4) << 12);
                        pA0 = *(const uint32x4*)(g0);
                        pA1 = *(const uint32x4*)(g0 + 4096);
                        pA2 = *(const uint32x4*)(g0 + 8192);
                        pA3 = *(const uint32x4*)(g0 + 12288);
                    }
                    char* dst = (char*)&pbuf[w][0][0] + lane * 16;
                    *(uint32x4*)(dst)        = pB0;
                    *(uint32x4*)(dst + 1024) = pB1;
                    *(uint32x4*)(dst + 2048) = pB2;
                    *(uint32x4*)(dst + 3072) = pB3;
                }
            }
        }
        asm volatile("s_waitcnt lgkmcnt(0)" ::: "memory");
        __builtin_amdgcn_s_barrier();
    }
#undef GBLOCK
#undef STEP

    if (wid == WV - 1 && l63) out[2 * B_ * N_ + b] = res;
}

extern "C" void kernel_launch(void* const* d_in, const int* in_sizes, int n_in,
                              void* d_out, int out_size, void* d_ws, size_t ws_size,
                              hipStream_t stream) {
    const float* x = (const float*)d_in[0];
    const float* y = (const float*)d_in[1];
    float* out = (float*)d_out;
    __half* dd2 = (__half*)d_ws;  // 4 MB fp16 packed table

    dim3 g1(N_ / 16, N_ / 16, B_);
    dist_h_kernel<<<g1, 256, 0, stream>>>(x, y, dd2);
    sdtw_pc4_kernel<<<B_, 512, 0, stream>>>(dd2, out);
}